// Round 10
// baseline (297.040 us; speedup 1.0000x reference)
//
#include <hip/hip_runtime.h>
#include <cstddef>

#define NPTS 4096
#define KNBR 80
#define CH   128
#define NF   (NPTS*CH)      // 524288
#define FFD  512
#define KSPLIT 8
#define NSPLIT 8            // attention key-split

typedef unsigned short ushort_t;
typedef short bf16x8 __attribute__((ext_vector_type(8)));
typedef float f32x4 __attribute__((ext_vector_type(4)));
typedef float f32x16 __attribute__((ext_vector_type(16)));

__device__ __forceinline__ unsigned short f2bf(float f){
    unsigned int u = __float_as_uint(f);
    unsigned int r = (u + 0x7FFFu + ((u >> 16) & 1u)) >> 16;
    return (unsigned short)r;
}

// pack two fp32 -> bf16 pair by truncation: low = hi16(a), high = hi16(b)
__device__ __forceinline__ unsigned pack2bf_trunc(float a, float b){
    return __builtin_amdgcn_perm(__float_as_uint(b), __float_as_uint(a), 0x07060302u);
}

__device__ __forceinline__ void load_lds16(const ushort_t* g, ushort_t* l){
    __builtin_amdgcn_global_load_lds(
        (const __attribute__((address_space(1))) unsigned int*)g,
        (__attribute__((address_space(3))) unsigned int*)l, 16, 0, 0);
}

// ---------------- prep: conv-W transpose+cast | dense-W cast | pos stats ----------------
// b < 2048  : Wt[f][n][k] = W_f[k][n] (bf16)
// b < 2816  : wbuf cast (Wq|Wk|Wv|Wo|W1|W2)
// b == 2816 : pos stats + zero BN accumulators
__global__ __launch_bounds__(256) void prep_kernel(
        const float* __restrict__ Wx, const float* __restrict__ Wy,
        ushort_t* __restrict__ Wt,
        const float* __restrict__ Wq, const float* __restrict__ Wk,
        const float* __restrict__ Wv, const float* __restrict__ Wo,
        const float* __restrict__ W1, const float* __restrict__ W2,
        ushort_t* __restrict__ wbuf,
        const float* __restrict__ pos, float* __restrict__ stats){
    __shared__ float tile[32][33];
    __shared__ float red[256];
    int b = blockIdx.x, t = threadIdx.x;
    if (b < 2048){
        int z = b >> 10, rem = b & 1023, kb = rem >> 2, nb = rem & 3;
        const float* W = z ? Wy : Wx;
        int tr = t & 31, tc = t >> 5;
        #pragma unroll
        for (int rr = 0; rr < 32; rr += 8)
            tile[tc+rr][tr] = W[(size_t)(kb*32 + tc + rr)*128 + nb*32 + tr];
        __syncthreads();
        size_t fo = (size_t)z * 8192 * 128;
        #pragma unroll
        for (int rr = 0; rr < 32; rr += 8)
            Wt[fo + (size_t)(nb*32 + tc + rr)*8192 + kb*32 + tr] = f2bf(tile[tr][tc+rr]);
    } else if (b < 2816){
        int i = (b - 2048)*256 + t;     // < 196608
        const float* src; int off;
        if      (i < 16384)  { src = Wq; off = i; }
        else if (i < 32768)  { src = Wk; off = i - 16384; }
        else if (i < 49152)  { src = Wv; off = i - 32768; }
        else if (i < 65536)  { src = Wo; off = i - 49152; }
        else if (i < 131072) { src = W1; off = i - 65536; }
        else                 { src = W2; off = i - 131072; }
        wbuf[i] = f2bf(src[off]);
    } else {
        stats[t] = 0.f;            // BN sum accumulators
        stats[256 + t] = 0.f;      // BN sumsq accumulators
        float s = 0.f;
        for (int i = t; i < NPTS; i += 256) s += pos[(size_t)i*3];
        red[t] = s; __syncthreads();
        for (int o = 128; o; o >>= 1){ if (t < o) red[t] += red[t+o]; __syncthreads(); }
        float mean = red[0] / (float)NPTS;
        __syncthreads();
        float ss = 0.f;
        for (int i = t; i < NPTS; i += 256){ float d = pos[(size_t)i*3] - mean; ss += d*d; }
        red[t] = ss; __syncthreads();
        for (int o = 128; o; o >>= 1){ if (t < o) red[t] += red[t+o]; __syncthreads(); }
        if (t == 0){
            float sd = sqrtf(red[0] / (float)(NPTS-1));
            stats[512] = mean;
            stats[513] = 1.f/(sd + 1e-8f);
        }
    }
}

// ---------------- cconv stage 1 (MFMA): A = Ct(64 x n) @ F(n x 128), both feats ----------------
__global__ __launch_bounds__(256) void cf_kernel(
        const float* __restrict__ xin, const float* __restrict__ yin,
        const float* __restrict__ pos, const int* __restrict__ nbr,
        ushort_t* __restrict__ Abuf, int base, int chunk){
    __shared__ ushort_t Ct[64*96];
    __shared__ ushort_t Ft[2][128*40];
    __shared__ int nbl[KNBR];
    __shared__ int cnt;
    int i = base + blockIdx.x;
    int t = threadIdx.x;
    for (int z = t; z < 64*96/8; z += 256) ((uint4*)Ct)[z] = uint4{0,0,0,0};
    if (t == 0) cnt = 0;
    __syncthreads();
    if (t < KNBR){
        int nb = nbr[(size_t)i*KNBR + t];
        if (nb != i){
            float p0 = pos[(size_t)i*3], p1 = pos[(size_t)i*3+1], p2 = pos[(size_t)i*3+2];
            const float RAD = 0.1125f;
            float rx = (pos[(size_t)nb*3+0]-p0)/RAD;
            float ry = (pos[(size_t)nb*3+1]-p1)/RAD;
            float rz = (pos[(size_t)nb*3+2]-p2)/RAD;
            float r2 = rx*rx + ry*ry + rz*rz;
            float w1 = 1.f - r2;
            float win = fminf(fmaxf(w1*w1*w1, 0.f), 1.f);
            float nrm = sqrtf(fmaxf(r2, 1e-12f));
            float linf = fmaxf(fmaxf(fabsf(rx), fabsf(ry)), fabsf(rz));
            linf = fmaxf(linf, 1e-9f);
            float sc = nrm/linf;
            float gx = fminf(fmaxf((rx*sc+1.f)*0.5f*3.f, 0.f), 3.f);
            float gy = fminf(fmaxf((ry*sc+1.f)*0.5f*3.f, 0.f), 3.f);
            float gz = fminf(fmaxf((rz*sc+1.f)*0.5f*3.f, 0.f), 3.f);
            float fx = fminf(floorf(gx), 2.f), fy = fminf(floorf(gy), 2.f), fz = fminf(floorf(gz), 2.f);
            float tx = gx-fx, ty = gy-fy, tz = gz-fz;
            int ix = (int)fx, iy = (int)fy, iz = (int)fz;
            int cb = (ix<<4) + (iy<<2) + iz;
            float x0 = (1.f-tx)*win, x1 = tx*win;
            float w00 = x0*(1.f-ty), w01 = x0*ty, w10 = x1*(1.f-ty), w11 = x1*ty;
            float z0 = 1.f-tz, z1 = tz;
            int slot = atomicAdd(&cnt, 1);
            nbl[slot] = nb;
            Ct[(cb     )*96 + slot] = f2bf(w00*z0);
            Ct[(cb + 1 )*96 + slot] = f2bf(w00*z1);
            Ct[(cb + 4 )*96 + slot] = f2bf(w01*z0);
            Ct[(cb + 5 )*96 + slot] = f2bf(w01*z1);
            Ct[(cb + 16)*96 + slot] = f2bf(w10*z0);
            Ct[(cb + 17)*96 + slot] = f2bf(w10*z1);
            Ct[(cb + 20)*96 + slot] = f2bf(w11*z0);
            Ct[(cb + 21)*96 + slot] = f2bf(w11*z1);
        }
    }
    __syncthreads();
    int n = cnt;
    int nch = (n + 31) >> 5;
    int lane = t & 63, w = t >> 6;
    int l15 = lane & 15, quad = lane >> 4;
    int jp = t & 15, cg = t >> 4;     // gather: j-pair 0..15, channel-group(8) 0..15
    f32x4 acc[2][8] = {};
    for (int ck = 0; ck < nch; ++ck){
        __syncthreads();
        int js0 = ck*32 + 2*jp;
        unsigned* F0 = (unsigned*)Ft[0];
        unsigned* F1 = (unsigned*)Ft[1];
        int ch0 = cg*8;
        if (js0 < n){
            float4 xa0, xa1, ya0, ya1;
            float4 xb0 = float4{0,0,0,0}, xb1 = float4{0,0,0,0};
            float4 yb0 = float4{0,0,0,0}, yb1 = float4{0,0,0,0};
            const float* sx = xin + (size_t)nbl[js0]*128 + ch0;
            const float* sy = yin + (size_t)nbl[js0]*128 + ch0;
            xa0 = *(const float4*)sx; xa1 = *(const float4*)(sx + 4);
            ya0 = *(const float4*)sy; ya1 = *(const float4*)(sy + 4);
            if (js0 + 1 < n){
                const float* tx2 = xin + (size_t)nbl[js0+1]*128 + ch0;
                const float* ty2 = yin + (size_t)nbl[js0+1]*128 + ch0;
                xb0 = *(const float4*)tx2; xb1 = *(const float4*)(tx2 + 4);
                yb0 = *(const float4*)ty2; yb1 = *(const float4*)(ty2 + 4);
            }
            F0[(ch0+0)*20 + jp] = pack2bf_trunc(xa0.x, xb0.x);
            F0[(ch0+1)*20 + jp] = pack2bf_trunc(xa0.y, xb0.y);
            F0[(ch0+2)*20 + jp] = pack2bf_trunc(xa0.z, xb0.z);
            F0[(ch0+3)*20 + jp] = pack2bf_trunc(xa0.w, xb0.w);
            F0[(ch0+4)*20 + jp] = pack2bf_trunc(xa1.x, xb1.x);
            F0[(ch0+5)*20 + jp] = pack2bf_trunc(xa1.y, xb1.y);
            F0[(ch0+6)*20 + jp] = pack2bf_trunc(xa1.z, xb1.z);
            F0[(ch0+7)*20 + jp] = pack2bf_trunc(xa1.w, xb1.w);
            F1[(ch0+0)*20 + jp] = pack2bf_trunc(ya0.x, yb0.x);
            F1[(ch0+1)*20 + jp] = pack2bf_trunc(ya0.y, yb0.y);
            F1[(ch0+2)*20 + jp] = pack2bf_trunc(ya0.z, yb0.z);
            F1[(ch0+3)*20 + jp] = pack2bf_trunc(ya0.w, yb0.w);
            F1[(ch0+4)*20 + jp] = pack2bf_trunc(ya1.x, yb1.x);
            F1[(ch0+5)*20 + jp] = pack2bf_trunc(ya1.y, yb1.y);
            F1[(ch0+6)*20 + jp] = pack2bf_trunc(ya1.z, yb1.z);
            F1[(ch0+7)*20 + jp] = pack2bf_trunc(ya1.w, yb1.w);
        } else {
            #pragma unroll
            for (int u = 0; u < 8; ++u){
                F0[(ch0+u)*20 + jp] = 0u;
                F1[(ch0+u)*20 + jp] = 0u;
            }
        }
        __syncthreads();
        bf16x8 af = *(const bf16x8*)(Ct + (size_t)(w*16 + l15)*96 + ck*32 + quad*8);
        #pragma unroll
        for (int f = 0; f < 2; ++f)
            #pragma unroll
            for (int nt = 0; nt < 8; ++nt){
                bf16x8 bfr = *(const bf16x8*)(Ft[f] + (size_t)(nt*16 + l15)*40 + quad*8);
                acc[f][nt] = __builtin_amdgcn_mfma_f32_16x16x32_bf16(af, bfr, acc[f][nt], 0, 0, 0);
            }
    }
    bool ev = !(l15 & 1);
    #pragma unroll
    for (int f = 0; f < 2; ++f){
        ushort_t* dst = Abuf + ((size_t)f*chunk + blockIdx.x)*8192;
        #pragma unroll
        for (int nt = 0; nt < 8; ++nt)
            #pragma unroll
            for (int reg = 0; reg < 4; ++reg){
                float v = acc[f][nt][reg];
                float p = __shfl_xor(v, 1);
                if (ev){
                    int cell = w*16 + quad*4 + reg;
                    *(unsigned*)(dst + (size_t)cell*128 + nt*16 + l15) = pack2bf_trunc(v, p);
                }
            }
    }
}

// ---------------- cconv stage 2: MFMA GEMM  P = A(bf16) @ Wt^T, split-K ----------------
__global__ __launch_bounds__(256) void mfma_gemm_kernel(
        const ushort_t* __restrict__ Abuf, const ushort_t* __restrict__ Wt,
        float* __restrict__ Pbuf, int chunk){
    __shared__ ushort_t Asm[128*64];
    __shared__ ushort_t Bsm[128*64];
    int tid = threadIdx.x, lane = tid & 63, w = tid >> 6;
    int feat = blockIdx.z >> 3, s = blockIdx.z & 7;
    const ushort_t* Ab = Abuf + (size_t)feat*chunk*8192 + (size_t)blockIdx.x*128*8192;
    const ushort_t* Bb = Wt + (size_t)feat*128*8192;
    int wm = w >> 1, wn = w & 1;
    int lr = lane >> 3, pb = lane & 7, lb = pb ^ lr;
    int quad = lane >> 4, l15 = lane & 15;
    int arow0 = w*32;
    f32x4 acc[4][4] = {};
    const int kk0 = s*(8192/KSPLIT), kk1 = kk0 + 8192/KSPLIT;
    for (int kk = kk0; kk < kk1; kk += 64){
        __syncthreads();
        #pragma unroll
        for (int q = 0; q < 4; ++q){
            int r = arow0 + q*8 + lr;
            load_lds16(Ab + (size_t)r*8192 + kk + lb*8, Asm + (arow0 + q*8)*64);
            load_lds16(Bb + (size_t)r*8192 + kk + lb*8, Bsm + (arow0 + q*8)*64);
        }
        __syncthreads();
        #pragma unroll
        for (int h = 0; h < 2; ++h){
            bf16x8 aF[4], bF[4];
            #pragma unroll
            for (int mt = 0; mt < 4; ++mt){
                int ml = wm*64 + mt*16 + l15;
                int p = (h*4 + quad) ^ (ml & 7);
                aF[mt] = *(const bf16x8*)(Asm + ml*64 + p*8);
            }
            #pragma unroll
            for (int nt = 0; nt < 4; ++nt){
                int nl = wn*64 + nt*16 + l15;
                int p = (h*4 + quad) ^ (nl & 7);
                bF[nt] = *(const bf16x8*)(Bsm + nl*64 + p*8);
            }
            #pragma unroll
            for (int mt = 0; mt < 4; ++mt)
                #pragma unroll
                for (int nt = 0; nt < 4; ++nt)
                    acc[mt][nt] = __builtin_amdgcn_mfma_f32_16x16x32_bf16(
                        aF[mt], bF[nt], acc[mt][nt], 0, 0, 0);
        }
    }
    float* P = Pbuf + (size_t)blockIdx.z*chunk*128 + (size_t)blockIdx.x*128*128;
    #pragma unroll
    for (int mt = 0; mt < 4; ++mt)
        #pragma unroll
        for (int nt = 0; nt < 4; ++nt)
            #pragma unroll
            for (int reg = 0; reg < 4; ++reg){
                int r = wm*64 + mt*16 + quad*4 + reg;
                int c = wn*64 + nt*16 + l15;
                P[(size_t)r*128 + c] = acc[mt][nt][reg];
            }
}

// ---------------- reduceP + fused BN partial stats ----------------
__global__ void reduceP_kernel(const float* __restrict__ P, float* __restrict__ hconv,
                               float* __restrict__ stats, int chunk, int base){
    __shared__ float ls[256], lq[256];
    int f = blockIdx.y, t = threadIdx.x;
    size_t base_idx = (size_t)blockIdx.x*2048 + t;
    float sum = 0.f, sq = 0.f;
    #pragma unroll
    for (int k = 0; k < 8; ++k){
        size_t idx = base_idx + (size_t)k*256;
        float s = 0.f;
        #pragma unroll
        for (int sp = 0; sp < KSPLIT; ++sp)
            s += P[((size_t)(f*KSPLIT + sp))*chunk*128 + idx];
        hconv[(size_t)f*NF + (size_t)base*128 + idx] = s;
        sum += s; sq += s*s;
    }
    ls[t] = sum; lq[t] = sq;
    __syncthreads();
    if (t < 128){
        atomicAdd(&stats[f*128 + t], ls[t] + ls[t+128]);
        atomicAdd(&stats[256 + f*128 + t], lq[t] + lq[t+128]);
    }
}

// ---------------- generic dense MFMA GEMM: D = A(M x K) @ B(N x K)^T ----------------
template<int MODE>
__global__ __launch_bounds__(256) void dgemm_kernel(
        const ushort_t* __restrict__ A, const ushort_t* __restrict__ Bw,
        const float* __restrict__ bs0, const float* __restrict__ bs1,
        const float* __restrict__ bs2,
        float* __restrict__ oF, ushort_t* __restrict__ oB0,
        ushort_t* __restrict__ oB1, ushort_t* __restrict__ oB2,
        int K, long aZ, long oZ){
    __shared__ ushort_t Asm[128*64];
    __shared__ ushort_t Bsm[128*64];
    int tid = threadIdx.x, lane = tid & 63, w = tid >> 6;
    int z = blockIdx.z;
    int f = (MODE == 2) ? (z/3) : z;
    int wsel = (MODE == 2) ? (z - 3*f) : 0;
    const ushort_t* Ab = A + (size_t)f*aZ + (size_t)blockIdx.x*128*K;
    const ushort_t* Bb = Bw + ((MODE == 2) ? (size_t)wsel*16384 : 0)
                            + (size_t)blockIdx.y*128*K;
    int wm = w >> 1, wn = w & 1;
    int lr = lane >> 3, pb = lane & 7, lb = pb ^ lr;
    int quad = lane >> 4, l15 = lane & 15;
    int arow0 = w*32;
    f32x4 acc[4][4] = {};
    for (int kk = 0; kk < K; kk += 64){
        __syncthreads();
        #pragma unroll
        for (int q = 0; q < 4; ++q){
            int r = arow0 + q*8 + lr;
            load_lds16(Ab + (size_t)r*K + kk + lb*8, Asm + (arow0 + q*8)*64);
            load_lds16(Bb + (size_t)r*K + kk + lb*8, Bsm + (arow0 + q*8)*64);
        }
        __syncthreads();
        #pragma unroll
        for (int h = 0; h < 2; ++h){
            bf16x8 aF[4], bF[4];
            #pragma unroll
            for (int mt = 0; mt < 4; ++mt){
                int ml = wm*64 + mt*16 + l15;
                int p = (h*4 + quad) ^ (ml & 7);
                aF[mt] = *(const bf16x8*)(Asm + ml*64 + p*8);
            }
            #pragma unroll
            for (int nt = 0; nt < 4; ++nt){
                int nl = wn*64 + nt*16 + l15;
                int p = (h*4 + quad) ^ (nl & 7);
                bF[nt] = *(const bf16x8*)(Bsm + nl*64 + p*8);
            }
            #pragma unroll
            for (int mt = 0; mt < 4; ++mt)
                #pragma unroll
                for (int nt = 0; nt < 4; ++nt)
                    acc[mt][nt] = __builtin_amdgcn_mfma_f32_16x16x32_bf16(
                        aF[mt], bF[nt], acc[mt][nt], 0, 0, 0);
        }
    }
    int r0 = blockIdx.x*128, c0 = blockIdx.y*128;
    const float* bias = bs0;
    float osc = 1.f;
    if (MODE == 2){
        bias = (wsel == 0) ? bs0 : (wsel == 1 ? bs1 : bs2);
        // Q scale: log2(e)/sqrt(32)  (softmax runs in exp2 domain)
        if (wsel == 0) osc = 0.25506764057565145f;
    }
    #pragma unroll
    for (int mt = 0; mt < 4; ++mt)
        #pragma unroll
        for (int nt = 0; nt < 4; ++nt)
            #pragma unroll
            for (int reg = 0; reg < 4; ++reg){
                int R = r0 + wm*64 + mt*16 + quad*4 + reg;
                int C = c0 + wn*64 + nt*16 + l15;
                float v = acc[mt][nt][reg];
                if (MODE == 0){
                    oF[(size_t)z*oZ + (size_t)R*128 + C] = v + bias[C];
                } else if (MODE == 1){
                    float r = fmaxf(v + bias[C], 0.f);
                    oB0[(size_t)z*2097152 + (size_t)R*512 + C] = f2bf(r);
                } else {
                    float r = (v + bias[C])*osc;
                    int hh = C >> 5, dd = C & 31;
                    if (wsel < 2){
                        ushort_t* dst = wsel ? oB1 : oB0;
                        dst[((size_t)(f*4+hh)*4096 + R)*32 + dd] = f2bf(r);
                    } else {
                        oB2[((size_t)(f*4+hh)*32 + dd)*4096 + R] = f2bf(r);
                    }
                }
            }
}

// bn apply (stats = raw sum/sumsq) + relu -> xf; h = xf + pe(inline) -> hb (bf16)
__global__ void bn_apply_kernel(const float* __restrict__ hconv, const float* __restrict__ stats,
        const float* __restrict__ gx, const float* __restrict__ bxp,
        const float* __restrict__ gy, const float* __restrict__ byp,
        const float* __restrict__ pos,
        float* __restrict__ xf, ushort_t* __restrict__ hb){
    int f = blockIdx.y;
    size_t idx = (size_t)blockIdx.x*256 + threadIdx.x;
    int ch = idx & 127;
    int i = (int)(idx >> 7);
    const float* g = f ? gy : gx;
    const float* b = f ? byp : bxp;
    float m  = stats[f*128 + ch] * (1.f/NPTS);
    float var = stats[256 + f*128 + ch] * (1.f/NPTS) - m*m;
    float inv = rsqrtf(var + 1e-5f);
    float vv = hconv[(size_t)f*NF + idx];
    float r = fmaxf((vv - m)*inv*g[ch] + b[ch], 0.f);
    xf[(size_t)f*NF + idx] = r;
    // positional encoding inline: m = ch>>1 -> dv = exp((ch&~1) * -ln(1e4)/128)
    float px = (pos[(size_t)i*3] - stats[512]) * stats[513];
    float dv = __expf((float)(ch & ~1) * -0.07195578415606394f);
    float ang = px * dv;
    float pe = (ch & 1) ? __cosf(ang) : __sinf(ang);
    hb[(size_t)f*NF + idx] = f2bf(r + pe);
}

// ---------------- MFMA flash attention: 32x32x16 fragments, key-split, Schraudolph ----------------
__global__ __launch_bounds__(256) void attn_mfma_kernel(
        const ushort_t* __restrict__ Qb, const ushort_t* __restrict__ Kb,
        const ushort_t* __restrict__ Vt, ushort_t* __restrict__ Opartb,
        float* __restrict__ ml){
    __shared__ ushort_t Kl[64*40];      // [key][d]  stride 40
    __shared__ ushort_t Vl[32*72];      // [d][key]  stride 72
    __shared__ ushort_t Pl[128*72];     // [q_local][key] stride 72, wave-private rows
    int tid = threadIdx.x, lane = tid & 63, w = tid >> 6;
    int q31 = lane & 31, hi = lane >> 5;
    int q0 = blockIdx.x*128;
    int head = blockIdx.y;
    int f = blockIdx.z >> 3, ksp = blockIdx.z & (NSPLIT-1);
    const ushort_t* Qh = Qb + ((size_t)(f*4+head)*4096)*32;
    const ushort_t* Kh = Kb + ((size_t)(f*4+head)*4096)*32;
    const ushort_t* Vh = Vt + ((size_t)(f*4+head)*32)*4096;
    int ql = w*32 + q31;
    int qg = q0 + ql;
    bf16x8 qfrag[2];
    qfrag[0] = *(const bf16x8*)(Qh + (size_t)qg*32 + hi*8);
    qfrag[1] = *(const bf16x8*)(Qh + (size_t)qg*32 + 16 + hi*8);
    f32x16 oacc = {};
    float lsum = 0.f;
    const float S23 = 8388608.0f;       // 2^23
    const float B23 = 1065353216.0f;    // 127 * 2^23
    int kr = tid >> 2, kseg = tid & 3;
    int vd = tid >> 3, vseg = tid & 7;
    for (int kt = 0; kt < 4096/NSPLIT/64; ++kt){
        int k0 = ksp*(4096/NSPLIT) + kt*64;
        uint4 tk = *(const uint4*)(Kh + (size_t)(k0+kr)*32 + kseg*8);
        uint4 tv = *(const uint4*)(Vh + (size_t)vd*4096 + k0 + vseg*8);
        __syncthreads();
        *(uint4*)(Kl + kr*40 + kseg*8) = tk;
        *(uint4*)(Vl + vd*72 + vseg*8) = tv;
        __syncthreads();
        #pragma unroll
        for (int mt = 0; mt < 2; ++mt){
            f32x16 sc = {};
            #pragma unroll
            for (int c = 0; c < 2; ++c){
                bf16x8 kf = *(const bf16x8*)(Kl + (size_t)(mt*32 + q31)*40 + c*16 + hi*8);
                sc = __builtin_amdgcn_mfma_f32_32x32x16_bf16(kf, qfrag[c], sc, 0, 0, 0);
            }
            #pragma unroll
            for (int r = 0; r < 4; ++r){
                unsigned i0 = (unsigned)fmaf(sc[4*r+0], S23, B23);
                unsigned i1 = (unsigned)fmaf(sc[4*r+1], S23, B23);
                unsigned i2 = (unsigned)fmaf(sc[4*r+2], S23, B23);
                unsigned i3 = (unsigned)fmaf(sc[4*r+3], S23, B23);
                lsum += (__uint_as_float(i0) + __uint_as_float(i1))
                      + (__uint_as_float(i2) + __uint_as_float(i3));
                uint2 pk;
                pk.x = __builtin_amdgcn_perm(i1, i0, 0x07060302u);
                pk.y = __builtin_amdgcn_perm(i3, i2, 0x07060302u);
                *(uint2*)(Pl + (size_t)ql*72 + mt*32 + r*8 + hi*4) = pk;
            }
        }
        #pragma unroll
        for (int kc = 0; kc < 4; ++kc){
            bf16x8 vf = *(const bf16x8*)(Vl + (size_t)q31*72 + kc*16 + hi*8);
            bf16x8 pf = *(const bf16x8*)(Pl + (size_t)ql*72 + kc*16 + hi*8);
            oacc = __builtin_amdgcn_mfma_f32_32x32x16_bf16(vf, pf, oacc, 0, 0, 0);
        }
    }
    lsum += __shfl_xor(lsum, 32);
    int slot = (f*4 + head)*NSPLIT + ksp;
    ushort_t* Op = Opartb + ((size_t)slot*4096 + qg)*32;
    #pragma unroll
    for (int r2 = 0; r2 < 4; ++r2){
        *(unsigned*)(Op + 8*r2 + 4*hi)     = pack2bf_trunc(oacc[4*r2+0], oacc[4*r2+1]);
        *(unsigned*)(Op + 8*r2 + 4*hi + 2) = pack2bf_trunc(oacc[4*r2+2], oacc[4*r2+3]);
    }
    if (hi == 0)
        ml[(size_t)slot*4096 + qg] = lsum;
}

// ---------------- attention split combine (plain sums) -> Ob (bf16 [f][q][128]) ----------------
__global__ void attn_combine_kernel(const ushort_t* __restrict__ Opartb,
        const float* __restrict__ ml, ushort_t* __restrict__ Ob){
    int gid = blockIdx.x*256 + threadIdx.x;     // < 2*4*4096*16 (d-pairs)
    int fh = gid >> 16;
    int rem = gid & 65535;
    int q = rem >> 4, d2 = rem & 15;
    float lsum = 0.f, o0 = 0.f, o1 = 0.f;
    #pragma unroll
    for (int s = 0; s < NSPLIT; ++s){
        lsum += ml[((size_t)fh*NSPLIT + s)*4096 + q];
        unsigned u = *(const unsigned*)(Opartb + (((size_t)(fh*NSPLIT + s))*4096 + q)*32 + 2*d2);
        o0 += __uint_as_float(u << 16);
        o1 += __uint_as_float(u & 0xFFFF0000u);
    }
    float inv = 1.f/lsum;
    int f = fh >> 2, head = fh & 3;
    *(unsigned*)(Ob + (size_t)f*NF + (size_t)q*128 + head*32 + 2*d2) =
        pack2bf_trunc(o0*inv, o1*inv);
}

// ---------------- LayerNorm(a + b), optional bf16 copy ----------------
__global__ __launch_bounds__(128) void ln_res_kernel(const float* __restrict__ a,
        const float* __restrict__ b, const float* __restrict__ g,
        const float* __restrict__ be, float* __restrict__ out,
        ushort_t* __restrict__ outB){
    __shared__ float red[128];
    int t = threadIdx.x;
    size_t off = (size_t)blockIdx.y*NF + (size_t)blockIdx.x*CH;
    float v = a[off + t] + b[off + t];
    red[t] = v; __syncthreads();
    for (int o = 64; o; o >>= 1){ if (t < o) red[t] += red[t+o]; __syncthreads(); }
    float m = red[0] / 128.f;
    __syncthreads();
    float d = v - m;
    red[t] = d*d; __syncthreads();
    for (int o = 64; o; o >>= 1){ if (t < o) red[t] += red[t+o]; __syncthreads(); }
    float var = red[0] / 128.f;
    float res = (v - m)*rsqrtf(var + 1e-5f)*g[t] + be[t];
    out[off + t] = res;
    if (outB) outB[off + t] = f2bf(res);
}

// ---------------- fused final: LN2 (both feats) + sigmoid gate ----------------
__global__ __launch_bounds__(128) void ln2_combine_kernel(
        const float* __restrict__ a, const float* __restrict__ b,
        const float* __restrict__ g, const float* __restrict__ be,
        const float* __restrict__ x, const float* __restrict__ y,
        float* __restrict__ out){
    __shared__ float red0[128], red1[128];
    int t = threadIdx.x;
    size_t off = (size_t)blockIdx.x*CH;
    float v0 = a[off + t] + b[off + t];
    float v1 = a[NF + off + t] + b[NF + off + t];
    red0[t] = v0; red1[t] = v1; __syncthreads();
    for (int o = 64; o; o >>= 1){
        if (t < o){ red0[t] += red0[t+o]; red1[t] += red1[t+o]; }
        __syncthreads();
    }
    float m0 = red0[0] / 128.f, m1 = red1[0] / 128.f;
    __syncthreads();
    float d0 = v0 - m0, d1 = v1 - m1;
    red0[t] = d0*d0; red1[t] = d1*d1; __syncthreads();
    for (int o = 64; o; o >>= 1){
        if (t < o){ red0[t] += red0[t+o]; red1[t] += red1[t+o]; }
        __syncthreads();
    }
    float r0 = d0*rsqrtf(red0[0]/128.f + 1e-5f)*g[t] + be[t];
    float r1 = d1*rsqrtf(red1[0]/128.f + 1e-5f)*g[t] + be[t];
    float wgt = 1.f/(1.f + __expf(-(r0 + r1)));
    out[off + t] = 2.f*x[off + t]*wgt + 2.f*y[off + t]*(1.f - wgt);
}

extern "C" void kernel_launch(void* const* d_in, const int* in_sizes, int n_in,
                              void* d_out, int out_size, void* d_ws, size_t ws_size,
                              hipStream_t stream){
    (void)in_sizes; (void)n_in; (void)out_size;
    const float* x    = (const float*)d_in[0];
    const float* y    = (const float*)d_in[1];
    const float* pos  = (const float*)d_in[2];
    const int*   nbr  = (const int*)  d_in[3];
    const float* Wx   = (const float*)d_in[5];
    const float* bnxg = (const float*)d_in[7];
    const float* bnxb = (const float*)d_in[8];
    const float* Wy   = (const float*)d_in[9];
    const float* bnyg = (const float*)d_in[11];
    const float* bnyb = (const float*)d_in[12];
    const float* Wq   = (const float*)d_in[13];
    const float* bq   = (const float*)d_in[14];
    const float* Wk   = (const float*)d_in[15];
    const float* bk   = (const float*)d_in[16];
    const float* Wv   = (const float*)d_in[17];
    const float* bv   = (const float*)d_in[18];
    const float* Wo   = (const float*)d_in[19];
    const float* bo   = (const float*)d_in[20];
    const float* ln1g = (const float*)d_in[21];
    const float* ln1b = (const float*)d_in[22];
    const float* W1   = (const float*)d_in[23];
    const float* b1   = (const float*)d_in[24];
    const float* W2   = (const float*)d_in[25];
    const float* b2   = (const float*)d_in[26];
    const float* ln2g = (const float*)d_in[27];
    const float* ln2b = (const float*)d_in[28];

    float* ws     = (float*)d_ws;
    float* hconv  = ws;                       // 2NF
    float* xf     = hconv + (size_t)2*NF;     // 2NF
    float* o2     = xf + (size_t)2*NF;        // 2NF
    float* feat1  = o2 + (size_t)2*NF;        // 2NF
    float* ff2    = feat1 + (size_t)2*NF;     // 2NF
    float* stats  = ff2 + (size_t)2*NF;       // 2048
    float* mlbuf  = stats + 2048;             // 2*4*NSPLIT*4096
    float* Pbuf   = mlbuf + (size_t)2*4*NSPLIT*4096;      // 2048*chunk

    const size_t fixedFloats = (size_t)10*NF + 2048 + (size_t)2*4*NSPLIT*4096;
    const size_t fixedUsh = (size_t)2097152 + 196608 + 6*1048576 + 4194304
                          + (size_t)2*4*NSPLIT*4096*32;   // + Opartb (bf16)
    int chunk = 128;
    const int cand[6] = {4096, 2048, 1024, 512, 256, 128};
    for (int ci = 0; ci < 6; ++ci){
        size_t need = (fixedFloats + (size_t)2048*cand[ci])*4
                    + (fixedUsh + (size_t)2*cand[ci]*8192)*2;
        if (need <= ws_size){ chunk = cand[ci]; break; }
    }
    ushort_t* Wt     = (ushort_t*)(Pbuf + (size_t)2048*chunk);
    ushort_t* wbuf   = Wt + 2097152;
    ushort_t* hb     = wbuf + 196608;
    ushort_t* Qb     = hb + 1048576;
    ushort_t* Kb     = Qb + 1048576;
    ushort_t* Vtb    = Kb + 1048576;
    ushort_t* Ob     = Vtb + 1048576;
    ushort_t* feat1b = Ob + 1048576;
    ushort_t* ff1b   = feat1b + 1048576;
    ushort_t* Opartb = ff1b + 4194304;
    ushort_t* Abuf   = Opartb + (size_t)2*4*NSPLIT*4096*32;

    prep_kernel<<<2817, 256, 0, stream>>>(Wx, Wy, Wt, Wq, Wk, Wv, Wo, W1, W2, wbuf, pos, stats);

    for (int base = 0; base < NPTS; base += chunk){
        cf_kernel<<<chunk, 256, 0, stream>>>(x, y, pos, nbr, Abuf, base, chunk);
        mfma_gemm_kernel<<<dim3(chunk/128, 1, 2*KSPLIT), 256, 0, stream>>>(Abuf, Wt, Pbuf, chunk);
        reduceP_kernel<<<dim3(chunk*128/2048, 2), 256, 0, stream>>>(Pbuf, hconv, stats, chunk, base);
    }

    bn_apply_kernel<<<dim3(NF/256, 2), 256, 0, stream>>>(hconv, stats, bnxg, bnxb, bnyg, bnyb,
                                                         pos, xf, hb);

    dgemm_kernel<2><<<dim3(32, 1, 6), 256, 0, stream>>>(hb, wbuf, bq, bk, bv,
        nullptr, Qb, Kb, Vtb, 128, (long)NF, 0);

    attn_mfma_kernel<<<dim3(32, 4, 2*NSPLIT), 256, 0, stream>>>(Qb, Kb, Vtb, Opartb, mlbuf);
    attn_combine_kernel<<<2048, 256, 0, stream>>>(Opartb, mlbuf, Ob);

    dgemm_kernel<0><<<dim3(32, 1, 2), 256, 0, stream>>>(Ob, wbuf + 49152, bo, nullptr, nullptr,
        o2, nullptr, nullptr, nullptr, 128, (long)NF, (long)NF);
    ln_res_kernel<<<dim3(NPTS, 2), 128, 0, stream>>>(xf, o2, ln1g, ln1b, feat1, feat1b);

    dgemm_kernel<1><<<dim3(32, 4, 2), 256, 0, stream>>>(feat1b, wbuf + 65536, b1, nullptr, nullptr,
        nullptr, ff1b, nullptr, nullptr, 128, (long)NF, 0);
    dgemm_kernel<0><<<dim3(32, 1, 2), 256, 0, stream>>>(ff1b, wbuf + 131072, b2, nullptr, nullptr,
        ff2, nullptr, nullptr, nullptr, 512, (long)2097152, (long)NF);

    ln2_combine_kernel<<<NPTS, 128, 0, stream>>>(feat1, ff2, ln2g, ln2b, x, y, (float*)d_out);
}

// Round 11
// 291.322 us; speedup vs baseline: 1.0196x; 1.0196x over previous
//
#include <hip/hip_runtime.h>
#include <cstddef>

#define NPTS 4096
#define KNBR 80
#define CH   128
#define NF   (NPTS*CH)      // 524288
#define FFD  512
#define KSPLIT 8
#define NSPLIT 8            // attention key-split

typedef unsigned short ushort_t;
typedef short bf16x8 __attribute__((ext_vector_type(8)));
typedef float f32x4 __attribute__((ext_vector_type(4)));
typedef float f32x16 __attribute__((ext_vector_type(16)));

__device__ __forceinline__ unsigned short f2bf(float f){
    unsigned int u = __float_as_uint(f);
    unsigned int r = (u + 0x7FFFu + ((u >> 16) & 1u)) >> 16;
    return (unsigned short)r;
}

// pack two fp32 -> bf16 pair by truncation: low = hi16(a), high = hi16(b)
__device__ __forceinline__ unsigned pack2bf_trunc(float a, float b){
    return __builtin_amdgcn_perm(__float_as_uint(b), __float_as_uint(a), 0x07060302u);
}

__device__ __forceinline__ void load_lds16(const ushort_t* g, ushort_t* l){
    __builtin_amdgcn_global_load_lds(
        (const __attribute__((address_space(1))) unsigned int*)g,
        (__attribute__((address_space(3))) unsigned int*)l, 16, 0, 0);
}

// ---------------- prep: conv-W transpose+cast | dense-W cast | pos stats ----------------
__global__ __launch_bounds__(256) void prep_kernel(
        const float* __restrict__ Wx, const float* __restrict__ Wy,
        ushort_t* __restrict__ Wt,
        const float* __restrict__ Wq, const float* __restrict__ Wk,
        const float* __restrict__ Wv, const float* __restrict__ Wo,
        const float* __restrict__ W1, const float* __restrict__ W2,
        ushort_t* __restrict__ wbuf,
        const float* __restrict__ pos, float* __restrict__ stats){
    __shared__ float tile[32][33];
    __shared__ float red[256];
    int b = blockIdx.x, t = threadIdx.x;
    if (b < 2048){
        int z = b >> 10, rem = b & 1023, kb = rem >> 2, nb = rem & 3;
        const float* W = z ? Wy : Wx;
        int tr = t & 31, tc = t >> 5;
        #pragma unroll
        for (int rr = 0; rr < 32; rr += 8)
            tile[tc+rr][tr] = W[(size_t)(kb*32 + tc + rr)*128 + nb*32 + tr];
        __syncthreads();
        size_t fo = (size_t)z * 8192 * 128;
        #pragma unroll
        for (int rr = 0; rr < 32; rr += 8)
            Wt[fo + (size_t)(nb*32 + tc + rr)*8192 + kb*32 + tr] = f2bf(tile[tr][tc+rr]);
    } else if (b < 2816){
        int i = (b - 2048)*256 + t;     // < 196608
        const float* src; int off;
        if      (i < 16384)  { src = Wq; off = i; }
        else if (i < 32768)  { src = Wk; off = i - 16384; }
        else if (i < 49152)  { src = Wv; off = i - 32768; }
        else if (i < 65536)  { src = Wo; off = i - 49152; }
        else if (i < 131072) { src = W1; off = i - 65536; }
        else                 { src = W2; off = i - 131072; }
        wbuf[i] = f2bf(src[off]);
    } else {
        stats[t] = 0.f;            // BN sum accumulators
        stats[256 + t] = 0.f;      // BN sumsq accumulators
        float s = 0.f;
        for (int i = t; i < NPTS; i += 256) s += pos[(size_t)i*3];
        red[t] = s; __syncthreads();
        for (int o = 128; o; o >>= 1){ if (t < o) red[t] += red[t+o]; __syncthreads(); }
        float mean = red[0] / (float)NPTS;
        __syncthreads();
        float ss = 0.f;
        for (int i = t; i < NPTS; i += 256){ float d = pos[(size_t)i*3] - mean; ss += d*d; }
        red[t] = ss; __syncthreads();
        for (int o = 128; o; o >>= 1){ if (t < o) red[t] += red[t+o]; __syncthreads(); }
        if (t == 0){
            float sd = sqrtf(red[0] / (float)(NPTS-1));
            stats[512] = mean;
            stats[513] = 1.f/(sd + 1e-8f);
        }
    }
}

// ---------------- cconv stage 1 (MFMA): A = Ct(64 x n) @ F(n x 128) -> bf16 ----------------
// Round-9 structure (per-feat passes, 23 KB LDS, low VGPR) + shfl-paired dword store.
__global__ __launch_bounds__(256) void cf_kernel(
        const float* __restrict__ xin, const float* __restrict__ yin,
        const float* __restrict__ pos, const int* __restrict__ nbr,
        ushort_t* __restrict__ Abuf, int base, int chunk){
    __shared__ ushort_t Ct[64*96];
    __shared__ ushort_t Ft[128*40];
    __shared__ int nbl[KNBR];
    __shared__ int cnt;
    int i = base + blockIdx.x;
    int t = threadIdx.x;
    for (int z = t; z < 64*96/8; z += 256) ((uint4*)Ct)[z] = uint4{0,0,0,0};
    if (t == 0) cnt = 0;
    __syncthreads();
    if (t < KNBR){
        int nb = nbr[(size_t)i*KNBR + t];
        if (nb != i){
            float p0 = pos[(size_t)i*3], p1 = pos[(size_t)i*3+1], p2 = pos[(size_t)i*3+2];
            const float RAD = 0.1125f;
            float rx = (pos[(size_t)nb*3+0]-p0)/RAD;
            float ry = (pos[(size_t)nb*3+1]-p1)/RAD;
            float rz = (pos[(size_t)nb*3+2]-p2)/RAD;
            float r2 = rx*rx + ry*ry + rz*rz;
            float w1 = 1.f - r2;
            float win = fminf(fmaxf(w1*w1*w1, 0.f), 1.f);
            float nrm = sqrtf(fmaxf(r2, 1e-12f));
            float linf = fmaxf(fmaxf(fabsf(rx), fabsf(ry)), fabsf(rz));
            linf = fmaxf(linf, 1e-9f);
            float sc = nrm/linf;
            float gx = fminf(fmaxf((rx*sc+1.f)*0.5f*3.f, 0.f), 3.f);
            float gy = fminf(fmaxf((ry*sc+1.f)*0.5f*3.f, 0.f), 3.f);
            float gz = fminf(fmaxf((rz*sc+1.f)*0.5f*3.f, 0.f), 3.f);
            float fx = fminf(floorf(gx), 2.f), fy = fminf(floorf(gy), 2.f), fz = fminf(floorf(gz), 2.f);
            float tx = gx-fx, ty = gy-fy, tz = gz-fz;
            int ix = (int)fx, iy = (int)fy, iz = (int)fz;
            int cb = (ix<<4) + (iy<<2) + iz;
            float x0 = (1.f-tx)*win, x1 = tx*win;
            float w00 = x0*(1.f-ty), w01 = x0*ty, w10 = x1*(1.f-ty), w11 = x1*ty;
            float z0 = 1.f-tz, z1 = tz;
            int slot = atomicAdd(&cnt, 1);
            nbl[slot] = nb;
            Ct[(cb     )*96 + slot] = f2bf(w00*z0);
            Ct[(cb + 1 )*96 + slot] = f2bf(w00*z1);
            Ct[(cb + 4 )*96 + slot] = f2bf(w01*z0);
            Ct[(cb + 5 )*96 + slot] = f2bf(w01*z1);
            Ct[(cb + 16)*96 + slot] = f2bf(w10*z0);
            Ct[(cb + 17)*96 + slot] = f2bf(w10*z1);
            Ct[(cb + 20)*96 + slot] = f2bf(w11*z0);
            Ct[(cb + 21)*96 + slot] = f2bf(w11*z1);
        }
    }
    __syncthreads();
    int n = cnt;
    int nch = (n + 31) >> 5;
    int lane = t & 63, w = t >> 6;
    int l15 = lane & 15, quad = lane >> 4;
    int jp = t & 15, cg = t >> 4;     // gather: j-pair 0..15, channel-group(8) 0..15
    bool ev = !(l15 & 1);
    for (int f = 0; f < 2; ++f){
        const float* feat = f ? yin : xin;
        f32x4 acc[8] = {};
        for (int ck = 0; ck < nch; ++ck){
            __syncthreads();
            int js0 = ck*32 + 2*jp;
            unsigned* Fd = (unsigned*)Ft;   // row stride 40 ushorts = 20 dwords
            int ch0 = cg*8;
            if (js0 < n){
                float4 a0, a1;
                float4 b0 = float4{0,0,0,0}, b1 = float4{0,0,0,0};
                const float* s0 = feat + (size_t)nbl[js0]*128 + ch0;
                a0 = *(const float4*)s0; a1 = *(const float4*)(s0 + 4);
                if (js0 + 1 < n){
                    const float* s1 = feat + (size_t)nbl[js0+1]*128 + ch0;
                    b0 = *(const float4*)s1; b1 = *(const float4*)(s1 + 4);
                }
                Fd[(ch0+0)*20 + jp] = pack2bf_trunc(a0.x, b0.x);
                Fd[(ch0+1)*20 + jp] = pack2bf_trunc(a0.y, b0.y);
                Fd[(ch0+2)*20 + jp] = pack2bf_trunc(a0.z, b0.z);
                Fd[(ch0+3)*20 + jp] = pack2bf_trunc(a0.w, b0.w);
                Fd[(ch0+4)*20 + jp] = pack2bf_trunc(a1.x, b1.x);
                Fd[(ch0+5)*20 + jp] = pack2bf_trunc(a1.y, b1.y);
                Fd[(ch0+6)*20 + jp] = pack2bf_trunc(a1.z, b1.z);
                Fd[(ch0+7)*20 + jp] = pack2bf_trunc(a1.w, b1.w);
            } else {
                #pragma unroll
                for (int u = 0; u < 8; ++u)
                    Fd[(ch0+u)*20 + jp] = 0u;
            }
            __syncthreads();
            bf16x8 af = *(const bf16x8*)(Ct + (size_t)(w*16 + l15)*96 + ck*32 + quad*8);
            #pragma unroll
            for (int nt = 0; nt < 8; ++nt){
                bf16x8 bfr = *(const bf16x8*)(Ft + (size_t)(nt*16 + l15)*40 + quad*8);
                acc[nt] = __builtin_amdgcn_mfma_f32_16x16x32_bf16(af, bfr, acc[nt], 0, 0, 0);
            }
        }
        ushort_t* dst = Abuf + ((size_t)f*chunk + blockIdx.x)*8192;
        #pragma unroll
        for (int nt = 0; nt < 8; ++nt)
            #pragma unroll
            for (int reg = 0; reg < 4; ++reg){
                float v = acc[nt][reg];
                float p = __shfl_xor(v, 1);
                if (ev){
                    int cell = w*16 + quad*4 + reg;
                    *(unsigned*)(dst + (size_t)cell*128 + nt*16 + l15) = pack2bf_trunc(v, p);
                }
            }
    }
}

// ---------------- cconv stage 2: MFMA GEMM, 64x128 tile, split-K ----------------
// grid (chunk/64, 1, 2*KSPLIT); 4 waves as 2x2 of 32x64.
__global__ __launch_bounds__(256) void mfma_gemm_kernel(
        const ushort_t* __restrict__ Abuf, const ushort_t* __restrict__ Wt,
        float* __restrict__ Pbuf, int chunk){
    __shared__ ushort_t Asm[64*64];
    __shared__ ushort_t Bsm[128*64];
    int tid = threadIdx.x, lane = tid & 63, w = tid >> 6;
    int feat = blockIdx.z >> 3, s = blockIdx.z & 7;
    const ushort_t* Ab = Abuf + (size_t)feat*chunk*8192 + (size_t)blockIdx.x*64*8192;
    const ushort_t* Bb = Wt + (size_t)feat*128*8192;
    int wm = w >> 1, wn = w & 1;
    int lr = lane >> 3, pb = lane & 7, lb = pb ^ lr;
    int quad = lane >> 4, l15 = lane & 15;
    f32x4 acc[2][4] = {};
    const int kk0 = s*(8192/KSPLIT), kk1 = kk0 + 8192/KSPLIT;
    for (int kk = kk0; kk < kk1; kk += 64){
        __syncthreads();
        #pragma unroll
        for (int q = 0; q < 2; ++q){
            int r = w*16 + q*8 + lr;
            load_lds16(Ab + (size_t)r*8192 + kk + lb*8, Asm + (w*16 + q*8)*64);
        }
        #pragma unroll
        for (int q = 0; q < 4; ++q){
            int r = w*32 + q*8 + lr;
            load_lds16(Bb + (size_t)r*8192 + kk + lb*8, Bsm + (w*32 + q*8)*64);
        }
        __syncthreads();
        #pragma unroll
        for (int h = 0; h < 2; ++h){
            bf16x8 aF[2], bF[4];
            #pragma unroll
            for (int mt = 0; mt < 2; ++mt){
                int ml = wm*32 + mt*16 + l15;
                int p = (h*4 + quad) ^ (ml & 7);
                aF[mt] = *(const bf16x8*)(Asm + ml*64 + p*8);
            }
            #pragma unroll
            for (int nt = 0; nt < 4; ++nt){
                int nl = wn*64 + nt*16 + l15;
                int p = (h*4 + quad) ^ (nl & 7);
                bF[nt] = *(const bf16x8*)(Bsm + nl*64 + p*8);
            }
            #pragma unroll
            for (int mt = 0; mt < 2; ++mt)
                #pragma unroll
                for (int nt = 0; nt < 4; ++nt)
                    acc[mt][nt] = __builtin_amdgcn_mfma_f32_16x16x32_bf16(
                        aF[mt], bF[nt], acc[mt][nt], 0, 0, 0);
        }
    }
    float* P = Pbuf + (size_t)blockIdx.z*chunk*128 + (size_t)blockIdx.x*64*128;
    #pragma unroll
    for (int mt = 0; mt < 2; ++mt)
        #pragma unroll
        for (int nt = 0; nt < 4; ++nt)
            #pragma unroll
            for (int reg = 0; reg < 4; ++reg){
                int r = wm*32 + mt*16 + quad*4 + reg;
                int c = wn*64 + nt*16 + l15;
                P[(size_t)r*128 + c] = acc[mt][nt][reg];
            }
}

// ---------------- reduceP + fused BN partial stats ----------------
__global__ void reduceP_kernel(const float* __restrict__ P, float* __restrict__ hconv,
                               float* __restrict__ stats, int chunk, int base){
    __shared__ float ls[256], lq[256];
    int f = blockIdx.y, t = threadIdx.x;
    size_t base_idx = (size_t)blockIdx.x*2048 + t;
    float sum = 0.f, sq = 0.f;
    #pragma unroll
    for (int k = 0; k < 8; ++k){
        size_t idx = base_idx + (size_t)k*256;
        float s = 0.f;
        #pragma unroll
        for (int sp = 0; sp < KSPLIT; ++sp)
            s += P[((size_t)(f*KSPLIT + sp))*chunk*128 + idx];
        hconv[(size_t)f*NF + (size_t)base*128 + idx] = s;
        sum += s; sq += s*s;
    }
    ls[t] = sum; lq[t] = sq;
    __syncthreads();
    if (t < 128){
        atomicAdd(&stats[f*128 + t], ls[t] + ls[t+128]);
        atomicAdd(&stats[256 + f*128 + t], lq[t] + lq[t+128]);
    }
}

// ---------------- generic dense MFMA GEMM, 64x128 tile: D = A(M x K) @ B(N x K)^T ----------------
template<int MODE>
__global__ __launch_bounds__(256) void dgemm_kernel(
        const ushort_t* __restrict__ A, const ushort_t* __restrict__ Bw,
        const float* __restrict__ bs0, const float* __restrict__ bs1,
        const float* __restrict__ bs2,
        float* __restrict__ oF, ushort_t* __restrict__ oB0,
        ushort_t* __restrict__ oB1, ushort_t* __restrict__ oB2,
        int K, long aZ, long oZ){
    __shared__ ushort_t Asm[64*64];
    __shared__ ushort_t Bsm[128*64];
    int tid = threadIdx.x, lane = tid & 63, w = tid >> 6;
    int z = blockIdx.z;
    int f = (MODE == 2) ? (z/3) : z;
    int wsel = (MODE == 2) ? (z - 3*f) : 0;
    const ushort_t* Ab = A + (size_t)f*aZ + (size_t)blockIdx.x*64*K;
    const ushort_t* Bb = Bw + ((MODE == 2) ? (size_t)wsel*16384 : 0)
                            + (size_t)blockIdx.y*128*K;
    int wm = w >> 1, wn = w & 1;
    int lr = lane >> 3, pb = lane & 7, lb = pb ^ lr;
    int quad = lane >> 4, l15 = lane & 15;
    f32x4 acc[2][4] = {};
    for (int kk = 0; kk < K; kk += 64){
        __syncthreads();
        #pragma unroll
        for (int q = 0; q < 2; ++q){
            int r = w*16 + q*8 + lr;
            load_lds16(Ab + (size_t)r*K + kk + lb*8, Asm + (w*16 + q*8)*64);
        }
        #pragma unroll
        for (int q = 0; q < 4; ++q){
            int r = w*32 + q*8 + lr;
            load_lds16(Bb + (size_t)r*K + kk + lb*8, Bsm + (w*32 + q*8)*64);
        }
        __syncthreads();
        #pragma unroll
        for (int h = 0; h < 2; ++h){
            bf16x8 aF[2], bF[4];
            #pragma unroll
            for (int mt = 0; mt < 2; ++mt){
                int ml = wm*32 + mt*16 + l15;
                int p = (h*4 + quad) ^ (ml & 7);
                aF[mt] = *(const bf16x8*)(Asm + ml*64 + p*8);
            }
            #pragma unroll
            for (int nt = 0; nt < 4; ++nt){
                int nl = wn*64 + nt*16 + l15;
                int p = (h*4 + quad) ^ (nl & 7);
                bF[nt] = *(const bf16x8*)(Bsm + nl*64 + p*8);
            }
            #pragma unroll
            for (int mt = 0; mt < 2; ++mt)
                #pragma unroll
                for (int nt = 0; nt < 4; ++nt)
                    acc[mt][nt] = __builtin_amdgcn_mfma_f32_16x16x32_bf16(
                        aF[mt], bF[nt], acc[mt][nt], 0, 0, 0);
        }
    }
    int r0 = blockIdx.x*64, c0 = blockIdx.y*128;
    const float* bias = bs0;
    float osc = 1.f;
    if (MODE == 2){
        bias = (wsel == 0) ? bs0 : (wsel == 1 ? bs1 : bs2);
        // Q scale: log2(e)/sqrt(32)  (softmax runs in exp2 domain)
        if (wsel == 0) osc = 0.25506764057565145f;
    }
    #pragma unroll
    for (int mt = 0; mt < 2; ++mt)
        #pragma unroll
        for (int nt = 0; nt < 4; ++nt)
            #pragma unroll
            for (int reg = 0; reg < 4; ++reg){
                int R = r0 + wm*32 + mt*16 + quad*4 + reg;
                int C = c0 + wn*64 + nt*16 + l15;
                float v = acc[mt][nt][reg];
                if (MODE == 0){
                    oF[(size_t)z*oZ + (size_t)R*128 + C] = v + bias[C];
                } else if (MODE == 1){
                    float r = fmaxf(v + bias[C], 0.f);
                    oB0[(size_t)z*2097152 + (size_t)R*512 + C] = f2bf(r);
                } else {
                    float r = (v + bias[C])*osc;
                    int hh = C >> 5, dd = C & 31;
                    if (wsel < 2){
                        ushort_t* dst = wsel ? oB1 : oB0;
                        dst[((size_t)(f*4+hh)*4096 + R)*32 + dd] = f2bf(r);
                    } else {
                        oB2[((size_t)(f*4+hh)*32 + dd)*4096 + R] = f2bf(r);
                    }
                }
            }
}

// bn apply (stats = raw sum/sumsq) + relu -> xf; h = xf + pe(inline) -> hb (bf16)
__global__ void bn_apply_kernel(const float* __restrict__ hconv, const float* __restrict__ stats,
        const float* __restrict__ gx, const float* __restrict__ bxp,
        const float* __restrict__ gy, const float* __restrict__ byp,
        const float* __restrict__ pos,
        float* __restrict__ xf, ushort_t* __restrict__ hb){
    int f = blockIdx.y;
    size_t idx = (size_t)blockIdx.x*256 + threadIdx.x;
    int ch = idx & 127;
    int i = (int)(idx >> 7);
    const float* g = f ? gy : gx;
    const float* b = f ? byp : bxp;
    float m  = stats[f*128 + ch] * (1.f/NPTS);
    float var = stats[256 + f*128 + ch] * (1.f/NPTS) - m*m;
    float inv = rsqrtf(var + 1e-5f);
    float vv = hconv[(size_t)f*NF + idx];
    float r = fmaxf((vv - m)*inv*g[ch] + b[ch], 0.f);
    xf[(size_t)f*NF + idx] = r;
    float px = (pos[(size_t)i*3] - stats[512]) * stats[513];
    float dv = __expf((float)(ch & ~1) * -0.07195578415606394f);
    float ang = px * dv;
    float pe = (ch & 1) ? __cosf(ang) : __sinf(ang);
    hb[(size_t)f*NF + idx] = f2bf(r + pe);
}

// ---------------- MFMA flash attention: 32x32x16 fragments, key-split, Schraudolph ----------------
__global__ __launch_bounds__(256) void attn_mfma_kernel(
        const ushort_t* __restrict__ Qb, const ushort_t* __restrict__ Kb,
        const ushort_t* __restrict__ Vt, ushort_t* __restrict__ Opartb,
        float* __restrict__ ml){
    __shared__ ushort_t Kl[64*40];      // [key][d]  stride 40
    __shared__ ushort_t Vl[32*72];      // [d][key]  stride 72
    __shared__ ushort_t Pl[128*72];     // [q_local][key] stride 72, wave-private rows
    int tid = threadIdx.x, lane = tid & 63, w = tid >> 6;
    int q31 = lane & 31, hi = lane >> 5;
    int q0 = blockIdx.x*128;
    int head = blockIdx.y;
    int f = blockIdx.z >> 3, ksp = blockIdx.z & (NSPLIT-1);
    const ushort_t* Qh = Qb + ((size_t)(f*4+head)*4096)*32;
    const ushort_t* Kh = Kb + ((size_t)(f*4+head)*4096)*32;
    const ushort_t* Vh = Vt + ((size_t)(f*4+head)*32)*4096;
    int ql = w*32 + q31;
    int qg = q0 + ql;
    bf16x8 qfrag[2];
    qfrag[0] = *(const bf16x8*)(Qh + (size_t)qg*32 + hi*8);
    qfrag[1] = *(const bf16x8*)(Qh + (size_t)qg*32 + 16 + hi*8);
    f32x16 oacc = {};
    float lsum = 0.f;
    const float S23 = 8388608.0f;       // 2^23
    const float B23 = 1065353216.0f;    // 127 * 2^23
    int kr = tid >> 2, kseg = tid & 3;
    int vd = tid >> 3, vseg = tid & 7;
    for (int kt = 0; kt < 4096/NSPLIT/64; ++kt){
        int k0 = ksp*(4096/NSPLIT) + kt*64;
        uint4 tk = *(const uint4*)(Kh + (size_t)(k0+kr)*32 + kseg*8);
        uint4 tv = *(const uint4*)(Vh + (size_t)vd*4096 + k0 + vseg*8);
        __syncthreads();
        *(uint4*)(Kl + kr*40 + kseg*8) = tk;
        *(uint4*)(Vl + vd*72 + vseg*8) = tv;
        __syncthreads();
        #pragma unroll
        for (int mt = 0; mt < 2; ++mt){
            f32x16 sc = {};
            #pragma unroll
            for (int c = 0; c < 2; ++c){
                bf16x8 kf = *(const bf16x8*)(Kl + (size_t)(mt*32 + q31)*40 + c*16 + hi*8);
                sc = __builtin_amdgcn_mfma_f32_32x32x16_bf16(kf, qfrag[c], sc, 0, 0, 0);
            }
            #pragma unroll
            for (int r = 0; r < 4; ++r){
                unsigned i0 = (unsigned)fmaf(sc[4*r+0], S23, B23);
                unsigned i1 = (unsigned)fmaf(sc[4*r+1], S23, B23);
                unsigned i2 = (unsigned)fmaf(sc[4*r+2], S23, B23);
                unsigned i3 = (unsigned)fmaf(sc[4*r+3], S23, B23);
                lsum += (__uint_as_float(i0) + __uint_as_float(i1))
                      + (__uint_as_float(i2) + __uint_as_float(i3));
                uint2 pk;
                pk.x = __builtin_amdgcn_perm(i1, i0, 0x07060302u);
                pk.y = __builtin_amdgcn_perm(i3, i2, 0x07060302u);
                *(uint2*)(Pl + (size_t)ql*72 + mt*32 + r*8 + hi*4) = pk;
            }
        }
        #pragma unroll
        for (int kc = 0; kc < 4; ++kc){
            bf16x8 vf = *(const bf16x8*)(Vl + (size_t)q31*72 + kc*16 + hi*8);
            bf16x8 pf = *(const bf16x8*)(Pl + (size_t)ql*72 + kc*16 + hi*8);
            oacc = __builtin_amdgcn_mfma_f32_32x32x16_bf16(vf, pf, oacc, 0, 0, 0);
        }
    }
    lsum += __shfl_xor(lsum, 32);
    int slot = (f*4 + head)*NSPLIT + ksp;
    ushort_t* Op = Opartb + ((size_t)slot*4096 + qg)*32;
    #pragma unroll
    for (int r2 = 0; r2 < 4; ++r2){
        *(unsigned*)(Op + 8*r2 + 4*hi)     = pack2bf_trunc(oacc[4*r2+0], oacc[4*r2+1]);
        *(unsigned*)(Op + 8*r2 + 4*hi + 2) = pack2bf_trunc(oacc[4*r2+2], oacc[4*r2+3]);
    }
    if (hi == 0)
        ml[(size_t)slot*4096 + qg] = lsum;
}

// ---------------- attention split combine (plain sums) -> Ob (bf16 [f][q][128]) ----------------
__global__ void attn_combine_kernel(const ushort_t* __restrict__ Opartb,
        const float* __restrict__ ml, ushort_t* __restrict__ Ob){
    int gid = blockIdx.x*256 + threadIdx.x;     // < 2*4*4096*16 (d-pairs)
    int fh = gid >> 16;
    int rem = gid & 65535;
    int q = rem >> 4, d2 = rem & 15;
    float lsum = 0.f, o0 = 0.f, o1 = 0.f;
    #pragma unroll
    for (int s = 0; s < NSPLIT; ++s){
        lsum += ml[((size_t)fh*NSPLIT + s)*4096 + q];
        unsigned u = *(const unsigned*)(Opartb + (((size_t)(fh*NSPLIT + s))*4096 + q)*32 + 2*d2);
        o0 += __uint_as_float(u << 16);
        o1 += __uint_as_float(u & 0xFFFF0000u);
    }
    float inv = 1.f/lsum;
    int f = fh >> 2, head = fh & 3;
    *(unsigned*)(Ob + (size_t)f*NF + (size_t)q*128 + head*32 + 2*d2) =
        pack2bf_trunc(o0*inv, o1*inv);
}

// ---------------- LayerNorm(a + b), optional bf16 copy ----------------
__global__ __launch_bounds__(128) void ln_res_kernel(const float* __restrict__ a,
        const float* __restrict__ b, const float* __restrict__ g,
        const float* __restrict__ be, float* __restrict__ out,
        ushort_t* __restrict__ outB){
    __shared__ float red[128];
    int t = threadIdx.x;
    size_t off = (size_t)blockIdx.y*NF + (size_t)blockIdx.x*CH;
    float v = a[off + t] + b[off + t];
    red[t] = v; __syncthreads();
    for (int o = 64; o; o >>= 1){ if (t < o) red[t] += red[t+o]; __syncthreads(); }
    float m = red[0] / 128.f;
    __syncthreads();
    float d = v - m;
    red[t] = d*d; __syncthreads();
    for (int o = 64; o; o >>= 1){ if (t < o) red[t] += red[t+o]; __syncthreads(); }
    float var = red[0] / 128.f;
    float res = (v - m)*rsqrtf(var + 1e-5f)*g[t] + be[t];
    out[off + t] = res;
    if (outB) outB[off + t] = f2bf(res);
}

// ---------------- fused final: LN2 (both feats) + sigmoid gate ----------------
__global__ __launch_bounds__(128) void ln2_combine_kernel(
        const float* __restrict__ a, const float* __restrict__ b,
        const float* __restrict__ g, const float* __restrict__ be,
        const float* __restrict__ x, const float* __restrict__ y,
        float* __restrict__ out){
    __shared__ float red0[128], red1[128];
    int t = threadIdx.x;
    size_t off = (size_t)blockIdx.x*CH;
    float v0 = a[off + t] + b[off + t];
    float v1 = a[NF + off + t] + b[NF + off + t];
    red0[t] = v0; red1[t] = v1; __syncthreads();
    for (int o = 64; o; o >>= 1){
        if (t < o){ red0[t] += red0[t+o]; red1[t] += red1[t+o]; }
        __syncthreads();
    }
    float m0 = red0[0] / 128.f, m1 = red1[0] / 128.f;
    __syncthreads();
    float d0 = v0 - m0, d1 = v1 - m1;
    red0[t] = d0*d0; red1[t] = d1*d1; __syncthreads();
    for (int o = 64; o; o >>= 1){
        if (t < o){ red0[t] += red0[t+o]; red1[t] += red1[t+o]; }
        __syncthreads();
    }
    float r0 = d0*rsqrtf(red0[0]/128.f + 1e-5f)*g[t] + be[t];
    float r1 = d1*rsqrtf(red1[0]/128.f + 1e-5f)*g[t] + be[t];
    float wgt = 1.f/(1.f + __expf(-(r0 + r1)));
    out[off + t] = 2.f*x[off + t]*wgt + 2.f*y[off + t]*(1.f - wgt);
}

extern "C" void kernel_launch(void* const* d_in, const int* in_sizes, int n_in,
                              void* d_out, int out_size, void* d_ws, size_t ws_size,
                              hipStream_t stream){
    (void)in_sizes; (void)n_in; (void)out_size;
    const float* x    = (const float*)d_in[0];
    const float* y    = (const float*)d_in[1];
    const float* pos  = (const float*)d_in[2];
    const int*   nbr  = (const int*)  d_in[3];
    const float* Wx   = (const float*)d_in[5];
    const float* bnxg = (const float*)d_in[7];
    const float* bnxb = (const float*)d_in[8];
    const float* Wy   = (const float*)d_in[9];
    const float* bnyg = (const float*)d_in[11];
    const float* bnyb = (const float*)d_in[12];
    const float* Wq   = (const float*)d_in[13];
    const float* bq   = (const float*)d_in[14];
    const float* Wk   = (const float*)d_in[15];
    const float* bk   = (const float*)d_in[16];
    const float* Wv   = (const float*)d_in[17];
    const float* bv   = (const float*)d_in[18];
    const float* Wo   = (const float*)d_in[19];
    const float* bo   = (const float*)d_in[20];
    const float* ln1g = (const float*)d_in[21];
    const float* ln1b = (const float*)d_in[22];
    const float* W1   = (const float*)d_in[23];
    const float* b1   = (const float*)d_in[24];
    const float* W2   = (const float*)d_in[25];
    const float* b2   = (const float*)d_in[26];
    const float* ln2g = (const float*)d_in[27];
    const float* ln2b = (const float*)d_in[28];

    float* ws     = (float*)d_ws;
    float* hconv  = ws;                       // 2NF
    float* xf     = hconv + (size_t)2*NF;     // 2NF
    float* o2     = xf + (size_t)2*NF;        // 2NF
    float* feat1  = o2 + (size_t)2*NF;        // 2NF
    float* ff2    = feat1 + (size_t)2*NF;     // 2NF
    float* stats  = ff2 + (size_t)2*NF;       // 2048
    float* mlbuf  = stats + 2048;             // 2*4*NSPLIT*4096
    float* Pbuf   = mlbuf + (size_t)2*4*NSPLIT*4096;      // 2048*chunk

    const size_t fixedFloats = (size_t)10*NF + 2048 + (size_t)2*4*NSPLIT*4096;
    const size_t fixedUsh = (size_t)2097152 + 196608 + 6*1048576 + 4194304
                          + (size_t)2*4*NSPLIT*4096*32;   // + Opartb (bf16)
    int chunk = 128;
    const int cand[6] = {4096, 2048, 1024, 512, 256, 128};
    for (int ci = 0; ci < 6; ++ci){
        size_t need = (fixedFloats + (size_t)2048*cand[ci])*4
                    + (fixedUsh + (size_t)2*cand[ci]*8192)*2;
        if (need <= ws_size){ chunk = cand[ci]; break; }
    }
    ushort_t* Wt     = (ushort_t*)(Pbuf + (size_t)2048*chunk);
    ushort_t* wbuf   = Wt + 2097152;
    ushort_t* hb     = wbuf + 196608;
    ushort_t* Qb     = hb + 1048576;
    ushort_t* Kb     = Qb + 1048576;
    ushort_t* Vtb    = Kb + 1048576;
    ushort_t* Ob     = Vtb + 1048576;
    ushort_t* feat1b = Ob + 1048576;
    ushort_t* ff1b   = feat1b + 1048576;
    ushort_t* Opartb = ff1b + 4194304;
    ushort_t* Abuf   = Opartb + (size_t)2*4*NSPLIT*4096*32;

    prep_kernel<<<2817, 256, 0, stream>>>(Wx, Wy, Wt, Wq, Wk, Wv, Wo, W1, W2, wbuf, pos, stats);

    for (int base = 0; base < NPTS; base += chunk){
        cf_kernel<<<chunk, 256, 0, stream>>>(x, y, pos, nbr, Abuf, base, chunk);
        mfma_gemm_kernel<<<dim3(chunk/64, 1, 2*KSPLIT), 256, 0, stream>>>(Abuf, Wt, Pbuf, chunk);
        reduceP_kernel<<<dim3(chunk*128/2048, 2), 256, 0, stream>>>(Pbuf, hconv, stats, chunk, base);
    }

    bn_apply_kernel<<<dim3(NF/256, 2), 256, 0, stream>>>(hconv, stats, bnxg, bnxb, bnyg, bnyb,
                                                         pos, xf, hb);

    dgemm_kernel<2><<<dim3(64, 1, 6), 256, 0, stream>>>(hb, wbuf, bq, bk, bv,
        nullptr, Qb, Kb, Vtb, 128, (long)NF, 0);

    attn_mfma_kernel<<<dim3(32, 4, 2*NSPLIT), 256, 0, stream>>>(Qb, Kb, Vtb, Opartb, mlbuf);
    attn_combine_kernel<<<2048, 256, 0, stream>>>(Opartb, mlbuf, Ob);

    dgemm_kernel<0><<<dim3(64, 1, 2), 256, 0, stream>>>(Ob, wbuf + 49152, bo, nullptr, nullptr,
        o2, nullptr, nullptr, nullptr, 128, (long)NF, (long)NF);
    ln_res_kernel<<<dim3(NPTS, 2), 128, 0, stream>>>(xf, o2, ln1g, ln1b, feat1, feat1b);

    dgemm_kernel<1><<<dim3(64, 4, 2), 256, 0, stream>>>(feat1b, wbuf + 65536, b1, nullptr, nullptr,
        nullptr, ff1b, nullptr, nullptr, 128, (long)NF, 0);
    dgemm_kernel<0><<<dim3(64, 1, 2), 256, 0, stream>>>(ff1b, wbuf + 131072, b2, nullptr, nullptr,
        ff2, nullptr, nullptr, nullptr, 512, (long)2097152, (long)NF);

    ln2_combine_kernel<<<NPTS, 128, 0, stream>>>(feat1, ff2, ln2g, ln2b, x, y, (float*)d_out);
}